// Round 7
// baseline (143.820 us; speedup 1.0000x reference)
//
#include <hip/hip_runtime.h>
#include <cmath>

#define NB   2048
#define ND   512
#define NL   8
#define NLAB 128
#define MAXM 64
#define TOPK_ 5
#define NTH  256             // per-subgroup thread count (stride in slot math)
#define NTH4 1024            // mega-block size: 4 subgroups
#define MAXSLOT 9            // ceil(64*65/2 / 256)
#define GSTRIDE (MAXM*MAXM)  // 4096 floats per (label,layer) gram

// ---------------------------------------------------------------------------
// R18. R17 post-mortem: static unroll -> VGPR 76, no change (scratch theory
// wrong). Block-scaling data (R16/R17: marginal serial layer = 5.6us, kernel
// = 43.2) + OccupancyPercent 12.7% (= exactly 4 waves = ONE 256-thr block/CU)
// => k_gram is block-residency bound: 1024 blocks run as 4 sequential rounds
// of 256. Fix: pack 4 (c,l) units into one 1024-thread block, 256 blocks =
// 1/CU = ONE round. Subgroup s (4 waves, private 34KB LDS slice, ~137KB tot,
// gfx950 allows >64KB/wg) = layer lbase+s of label bx>>1. m is uniform per
// block (same c) -> all __syncthreads uniform; phase-1 skeleton only in odd
// blocks (uniform). All FP order identical to R13/R17 -> absmax 0.0.
// Bucket scan: register bitmask+popcount (no dynamic-indexed my[] -> no
// scratch); subgroups compute it redundantly (same values, benign).
// Experiment value: if k_gram4 stays ~43us, serializer is memory queueing,
// not residency -> next lever is gather-traffic reduction.
// ---------------------------------------------------------------------------
#define SLOT_DECL(s) int off##s = -1; int lds##s = 0; float4 pre##s;
#define SLOT_INIT(s) { int idx = tid + (s)*NTH; if (idx < (m << 5)) { \
    int i = idx >> 5, k4 = idx & 31; \
    off##s = (g_s[i] << 9) + (k4 << 2); \
    lds##s = i * 132 + (k4 << 2); \
    pre##s = *(const float4*)(X + off##s); } }
#define SLOT_STORE(s) if (off##s >= 0) *(float4*)(XtF + lds##s) = pre##s;
#define SLOT_FETCH(s, kcn) if (off##s >= 0) pre##s = *(const float4*)(X + off##s + (kcn));

__global__ __launch_bounds__(NTH4) void k_gram4(
    const float* __restrict__ feats, const int* __restrict__ labels,
    float* __restrict__ G, int* __restrict__ cnt,
    unsigned long long* __restrict__ insub)
{
    __shared__ float Xt[4][MAXM][132];   // per-subgroup staging / gram tile (135168 B)
    __shared__ int   g_s[MAXM];          // shared: same label for all subgroups
    __shared__ int   wsum[4][4];         // per-subgroup scan partials
    __shared__ float rinvp[4][64];
    __shared__ unsigned long long tops_s[64];   // phase-1 only (subgroup 3 of odd blocks)
    __shared__ unsigned char keep_s[64];

    int bx = blockIdx.x;
    int c = bx >> 1;
    int lbase = (bx & 1) << 2;
    int sub = threadIdx.x >> 8;          // 0..3 (wave-aligned subgroups)
    int tid = threadIdx.x & 255;         // sub-local id; all legacy code uses this
    int l = lbase + sub;
    int lane = tid & 63, wv = tid >> 6;
    float* XtF = &Xt[sub][0][0];

    // ---- bucket scan via register bitmask (no dynamic arrays) ----
    int base_i = tid * 8;
    unsigned mask = 0u;
    #pragma unroll
    for (int t = 0; t < 8; ++t)
        if (labels[base_i + t] == c) mask |= (1u << t);
    int n = __popc(mask);
    int scan = n;
    #pragma unroll
    for (int off = 1; off < 64; off <<= 1) {
        int v = __shfl_up(scan, off);
        if (lane >= off) scan += v;
    }
    if (lane == 63) wsum[sub][wv] = scan;
    __syncthreads();
    int w0 = wsum[sub][0], w1 = wsum[sub][1], w2 = wsum[sub][2], w3 = wsum[sub][3];
    int m = w0 + w1 + w2 + w3; if (m > MAXM) m = MAXM;
    int base = (wv > 0 ? w0 : 0) + (wv > 1 ? w1 : 0) + (wv > 2 ? w2 : 0);
    int excl = base + scan - n;
    #pragma unroll
    for (int t = 0; t < 8; ++t) {
        if ((mask >> t) & 1u) {
            int slot = excl + __popc(mask & ((1u << t) - 1u));
            if (slot < MAXM) g_s[slot] = base_i + t;   // subgroups write identical values
        }
    }
    if (l == 0 && tid == 0) cnt[c] = m;
    __syncthreads();
    if (m == 0) {                         // m uniform across block -> uniform return
        if (lbase == 4 && sub == 3 && tid == 0) insub[c] = 0ull;
        return;
    }

    const float* X = feats + (size_t)l * NB * ND;

    // ---- scalar staging slots; prefetch chunk 0 ----
    SLOT_DECL(0) SLOT_DECL(1) SLOT_DECL(2) SLOT_DECL(3)
    SLOT_DECL(4) SLOT_DECL(5) SLOT_DECL(6) SLOT_DECL(7)
    SLOT_INIT(0) SLOT_INIT(1) SLOT_INIT(2) SLOT_INIT(3)
    SLOT_INIT(4) SLOT_INIT(5) SLOT_INIT(6) SLOT_INIT(7)

    // ---- triangular slot decode, statically unrolled (VGPR-resident) ----
    const int P = m * (m + 1) / 2;
    float acc0[MAXSLOT], acc1[MAXSLOT];
    int   ii_[MAXSLOT], jj_[MAXSLOT];
    #pragma unroll
    for (int s = 0; s < MAXSLOT; ++s) {
        int p = tid + s * NTH;
        int iv = -1, jv = 0;
        if (p < P) {
            int i = (int)((sqrtf(8.0f * (float)p + 1.0f) - 1.0f) * 0.5f);
            while (((i + 1) * (i + 2)) / 2 <= p) ++i;
            while ((i * (i + 1)) / 2 > p) --i;
            iv = i; jv = p - (i * (i + 1)) / 2;
        }
        ii_[s] = iv; jj_[s] = jv;
        acc0[s] = 0.0f; acc1[s] = 0.0f;
    }

    // ---- pipelined K-loop (uniform trip counts across subgroups) ----
    for (int kc = 0; kc < ND; kc += 128) {
        if (kc) __syncthreads();
        SLOT_STORE(0) SLOT_STORE(1) SLOT_STORE(2) SLOT_STORE(3)
        SLOT_STORE(4) SLOT_STORE(5) SLOT_STORE(6) SLOT_STORE(7)
        __syncthreads();
        if (kc + 128 < ND) {
            int kcn = kc + 128;
            SLOT_FETCH(0, kcn) SLOT_FETCH(1, kcn) SLOT_FETCH(2, kcn) SLOT_FETCH(3, kcn)
            SLOT_FETCH(4, kcn) SLOT_FETCH(5, kcn) SLOT_FETCH(6, kcn) SLOT_FETCH(7, kcn)
        }
        #pragma unroll
        for (int s = 0; s < MAXSLOT; ++s) {
            if (ii_[s] >= 0) {
                const float* ra = &Xt[sub][ii_[s]][0];
                const float* rb = &Xt[sub][jj_[s]][0];
                float a0 = acc0[s], a1 = acc1[s];
                #pragma unroll
                for (int k4 = 0; k4 < 32; ++k4) {
                    float4 a = *(const float4*)(ra + (k4 << 2));
                    float4 b = *(const float4*)(rb + (k4 << 2));
                    a0 = fmaf(a.x, b.x, a0); a1 = fmaf(a.y, b.y, a1);
                    a0 = fmaf(a.z, b.z, a0); a1 = fmaf(a.w, b.w, a1);
                }
                acc0[s] = a0; acc1[s] = a1;
            }
        }
    }

    // ---- stage raw tile (reuse Xt[sub]), normalize in place, store ----
    float (*Gs)[65] = (float(*)[65])(&Xt[sub][0][0]);
    __syncthreads();
    #pragma unroll
    for (int s = 0; s < MAXSLOT; ++s) {
        if (ii_[s] >= 0) {
            float v = acc0[s] + acc1[s];
            Gs[ii_[s]][jj_[s]] = v; Gs[jj_[s]][ii_[s]] = v;
        }
    }
    if (tid < m) for (int j = m; j < 64; ++j) Gs[tid][j] = -2.0f;
    __syncthreads();
    if (tid < 64) rinvp[sub][tid] = (tid < m) ? 1.0f / fmaxf(sqrtf(Gs[tid][tid]), 1e-8f) : 0.0f;
    __syncthreads();
    for (int idx = tid; idx < (m << 6); idx += NTH) {
        int i = idx >> 6, j = idx & 63;
        if (j < m) {
            float raw = Gs[i][j];
            Gs[i][j] = fminf(fmaxf(raw * rinvp[sub][i] * rinvp[sub][j], -1.0f), 1.0f);
        }
    }
    __syncthreads();
    float* Gc = G + ((size_t)l * NLAB + c) * GSTRIDE;
    for (int idx4 = tid; idx4 < (m << 4); idx4 += NTH) {
        int i = idx4 >> 4, j0 = (idx4 & 15) << 2;
        *(float4*)(Gc + i * MAXM + j0) = *(const float4*)&Gs[i][j0];
    }

    // ---- phase-1 skeleton: odd blocks only (uniform); work on subgroup 3 ----
    if (lbase == 4) {
        if (sub == 3 && tid < 64) { keep_s[tid] = 0; tops_s[tid] = 0ull; }
        __syncthreads();
        unsigned long long tops = 0ull; bool keep = false;
        if (sub == 3 && tid < m) {
            float v0=-1.f,v1=-1.f,v2=-1.f,v3=-1.f,v4=-1.f;
            int i0=0,i1=0,i2=0,i3=0,i4=0, cand=0;
            #pragma unroll 8
            for (int j = 0; j < 64; ++j) {
                float v = Gs[tid][j];          // normalized, or -2 sentinel
                if (v > 0.0f && j != tid) {
                    ++cand;
                    if      (v > v0) { v4=v3;i4=i3; v3=v2;i3=i2; v2=v1;i2=i1; v1=v0;i1=i0; v0=v;i0=j; }
                    else if (v > v1) { v4=v3;i4=i3; v3=v2;i3=i2; v2=v1;i2=i1; v1=v;i1=j; }
                    else if (v > v2) { v4=v3;i4=i3; v3=v2;i3=i2; v2=v;i2=j; }
                    else if (v > v3) { v4=v3;i4=i3; v3=v;i3=j; }
                    else if (v > v4) { v4=v;i4=j; }
                }
            }
            keep = (cand >= TOPK_);
            if (keep) tops = (1ull<<i0)|(1ull<<i1)|(1ull<<i2)|(1ull<<i3)|(1ull<<i4);
            keep_s[tid] = keep ? 1 : 0; tops_s[tid] = tops;
        }
        __syncthreads();
        if (sub == 3) {
            unsigned long long Mrow = 0ull;
            if (tid < m && keep) {
                for (int j = 0; j < 64; ++j) {
                    if (j == tid || !keep_s[j]) continue;
                    if (((tops >> j) & 1ull) || ((tops_s[j] >> tid) & 1ull)) Mrow |= (1ull << j);
                }
            }
            if (tid < 64) {
                unsigned long long b = __ballot(Mrow != 0ull);
                if (tid == 0) insub[c] = b;
            }
        }
    }
}

// ---------------------------------------------------------------------------
// Per (label, pair p): load normalized tiles for layers p,p+1; decide(p) on
// wave 0 and decide(p+1) on wave 1 concurrently; masked pair reduce from LDS.
// (Unchanged from R13/R17 -- one-variable experiment.)
// ---------------------------------------------------------------------------
__global__ __launch_bounds__(NTH) void k_pairdec(
    const float* __restrict__ G, const int* __restrict__ cnt,
    const unsigned long long* __restrict__ insub,
    float* __restrict__ partial)   // [NL-1][NLAB][4]
{
    __shared__ float Gs0[64][65];
    __shared__ float Gs1[64][65];
    __shared__ unsigned long long tops0[64], tops1[64];
    __shared__ unsigned char keep0[64], keep1[64];
    __shared__ unsigned long long M0s[64], M1s[64];
    __shared__ float es[64];
    __shared__ float red[12];      // 4 waves x 3
    int c = blockIdx.x, p = blockIdx.y, tid = threadIdx.x;
    int lane = tid & 63, wv = tid >> 6;
    int m = cnt[c]; if (m > MAXM) m = MAXM;
    unsigned long long sub = insub[c];

    const float* G0 = G + ((size_t)p       * NLAB + c) * GSTRIDE;
    const float* G1 = G + ((size_t)(p + 1) * NLAB + c) * GSTRIDE;
    for (int idx4 = tid; idx4 < (m << 4); idx4 += NTH) {
        int i = idx4 >> 4, j0 = (idx4 & 15) << 2;
        *(float4*)&Gs0[i][j0] = *(const float4*)(G0 + i * MAXM + j0);
        *(float4*)&Gs1[i][j0] = *(const float4*)(G1 + i * MAXM + j0);
    }
    if (tid < 64)       { keep0[tid] = 0; tops0[tid] = 0ull; }
    else if (tid < 128) { keep1[tid - 64] = 0; tops1[tid - 64] = 0ull; }
    __syncthreads();

    unsigned long long tops = 0ull; bool keep = false;
    if (wv < 2 && lane < m) {
        const float (*Gt)[65] = (wv == 0) ? Gs0 : Gs1;
        bool act = (sub >> lane) & 1ull;
        float emaval = 0.0f;
        if (act) {
            float v0=-1.f,v1=-1.f,v2=-1.f,v3=-1.f,v4=-1.f;
            int i0=0,i1=0,i2=0,i3=0,i4=0, cand=0, dg=0;
            float rs = 0.0f;
            #pragma unroll 8
            for (int j = 0; j < 64; ++j) {
                float v = Gt[lane][j];
                if (!((sub >> j) & 1ull)) v = -2.0f;
                if (v > 0.0f) {
                    rs += v; ++dg;                  // includes j == lane (diag ~ 1.0)
                    if (j != lane) {
                        ++cand;
                        if      (v > v0) { v4=v3;i4=i3; v3=v2;i3=i2; v2=v1;i2=i1; v1=v0;i1=i0; v0=v;i0=j; }
                        else if (v > v1) { v4=v3;i4=i3; v3=v2;i3=i2; v2=v1;i2=i1; v1=v;i1=j; }
                        else if (v > v2) { v4=v3;i4=i3; v3=v2;i3=i2; v2=v;i2=j; }
                        else if (v > v3) { v4=v3;i4=i3; v3=v;i3=j; }
                        else if (v > v4) { v4=v;i4=j; }
                    }
                }
            }
            keep = (cand >= TOPK_);
            if (keep) tops = (1ull<<i0)|(1ull<<i1)|(1ull<<i2)|(1ull<<i3)|(1ull<<i4);
            float deg = (float)(dg > 0 ? dg : 1);
            float score = 1.0f / (1.0f + expf(-rs / deg));
            emaval = 0.45f + 0.1f * score;          // MOM*0.5 + (1-MOM)*score
        }
        if (wv == 0) { keep0[lane] = keep ? 1 : 0; tops0[lane] = tops; es[lane] = emaval; }
        else         { keep1[lane] = keep ? 1 : 0; tops1[lane] = tops; }
    }
    __syncthreads();
    if (wv < 2 && lane < m) {
        const unsigned long long* topsW = (wv == 0) ? tops0 : tops1;
        const unsigned char*     keepW = (wv == 0) ? keep0 : keep1;
        unsigned long long Mrow = 0ull;
        if (keep) {
            for (int j = 0; j < 64; ++j) {
                if (j == lane || !keepW[j]) continue;
                if (((tops >> j) & 1ull) || ((topsW[j] >> lane) & 1ull)) Mrow |= (1ull << j);
            }
        }
        if (wv == 0) M0s[lane] = Mrow; else M1s[lane] = Mrow;
    }
    __syncthreads();

    float fn = 0.0f, fd = 0.0f, fc = 0.0f;
    for (int idx = tid; idx < (m << 6); idx += NTH) {
        int i = idx >> 6, j = idx & 63;
        if (j >= m) continue;
        bool b0 = (M0s[i] >> j) & 1ull;
        bool b1 = (M1s[i] >> j) & 1ull;
        if (b0 | b1) {
            float v0 = b0 ? Gs0[i][j] : 0.0f;   // normalized+clipped in k_gram4
            float v1 = b1 ? Gs1[i][j] : 0.0f;
            float w = es[i] * es[j];
            float d = v1 - v0;
            fn = fmaf(d * d, w, fn);
            fd += w;
            fc += 1.0f;
        }
    }
    for (int off = 32; off > 0; off >>= 1) {
        fn += __shfl_down(fn, off);
        fd += __shfl_down(fd, off);
        fc += __shfl_down(fc, off);
    }
    if ((tid & 63) == 0) { red[wv * 3] = fn; red[wv * 3 + 1] = fd; red[wv * 3 + 2] = fc; }
    __syncthreads();
    if (tid == 0) {
        float* dst = partial + ((size_t)p * NLAB + c) * 4;
        dst[0] = red[0] + red[3] + red[6] + red[9];
        dst[1] = red[1] + red[4] + red[7] + red[10];
        dst[2] = red[2] + red[5] + red[8] + red[11];
    }
}

// Single-wave final reduction over 896 private slots (~14 KB, L2-hit).
__global__ void k_final(const float* __restrict__ partial, float* __restrict__ out)
{
    int tid = threadIdx.x;
    float total = 0.0f;
    for (int p = 0; p < NL - 1; ++p) {
        float n = 0.0f, d = 0.0f, cc = 0.0f;
        for (int c = tid; c < NLAB; c += 64) {
            const float* src = partial + ((size_t)p * NLAB + c) * 4;
            n += src[0]; d += src[1]; cc += src[2];
        }
        for (int off = 32; off > 0; off >>= 1) {
            n += __shfl_down(n, off);
            d += __shfl_down(d, off);
            cc += __shfl_down(cc, off);
        }
        if (tid == 0 && cc > 0.0f) total += n / fmaxf(d, 1e-8f);
    }
    if (tid == 0) out[0] = 16.0f * total / 7.0f;   // LAMBDA_ALIGN_K * sum / (L-1)
}

extern "C" void kernel_launch(void* const* d_in, const int* in_sizes, int n_in,
                              void* d_out, int out_size, void* d_ws, size_t ws_size,
                              hipStream_t stream) {
    const float* feats  = (const float*)d_in[0];
    const int*   labels = (const int*)d_in[1];
    // (sample_ids unused by the reference)
    char* w = (char*)d_ws;
    size_t gbytes = (size_t)NL * NLAB * GSTRIDE * 4;                 // 16,777,216
    float*    G       = (float*)(w);                                 // normalized grams
    float*    partial = (float*)(w + gbytes);                        // 14,336 B
    int*      cnt     = (int*)(w + gbytes + 14336);                  // 512 B
    unsigned long long* insub = (unsigned long long*)(w + gbytes + 14848);   // 1,024 B
    float*    out     = (float*)d_out;

    k_gram4  <<<dim3(NLAB * NL / 4), NTH4, 0, stream>>>(feats, labels, G, cnt, insub);
    k_pairdec<<<dim3(NLAB, NL - 1),  NTH,  0, stream>>>(G, cnt, insub, partial);
    k_final  <<<1, 64, 0, stream>>>(partial, out);
}